// Round 5
// baseline (648.261 us; speedup 1.0000x reference)
//
#include <hip/hip_runtime.h>
#include <cstdint>
#include <cstddef>

// GNNGuard: 2-layer GCN, N=100000 nodes, E=1.6M edges, 512->128->16, log_softmax.
// R5: fuse GEMM2 into agg1 epilogue (in-wave 128x16 matvec + shfl butterfly),
// h2 stored bf16 (fits per-XCD L2), agg1 edge loop unrolled x2 for MLP.

#define NFEAT 512
#define NHID 128
#define NCLASS 16

typedef __attribute__((ext_vector_type(8))) __bf16 bf16x8;
typedef __attribute__((ext_vector_type(4))) float f32x4;

// ---------------- W1 pre-pack into MFMA B-fragment order ----------------
// Layout: [kstep 0..15][nchunk 0..7][lane 0..63][j 0..7]
// value = bf16( W1[k = kstep*32 + (lane>>4)*8 + j][n = nchunk*16 + (lane&15)] )
__global__ void k_prep_w1(const float* __restrict__ W1, __bf16* __restrict__ W1f) {
    int t = blockIdx.x * 256 + threadIdx.x;
    if (t >= 16 * 8 * 64) return;
    int lane = t & 63;
    int nc = (t >> 6) & 7;
    int ks = t >> 9;
    int q = lane >> 4, col = lane & 15;
    __bf16* outp = W1f + (size_t)t * 8;
#pragma unroll
    for (int j = 0; j < 8; j++) {
        int k = ks * 32 + q * 8 + j;
        int n = nc * 16 + col;
        outp[j] = (__bf16)W1[k * NHID + n];
    }
}

// ---------------- CSR build ----------------
// Pass 1: histogram + save each edge's within-node rank (atomic return value).
__global__ void k_count_rank(const int* __restrict__ dst, int* __restrict__ cnt,
                             int* __restrict__ rank, int E) {
    int e = blockIdx.x * 256 + threadIdx.x;
    if (e < E) rank[e] = atomicAdd(&cnt[dst[e]], 1);
}

// Block-level partial sums: block b sums cnt[b*1024 .. b*1024+1023]
__global__ void k_bsum(const int* __restrict__ cnt, int* __restrict__ bs, int N) {
    int b = blockIdx.x, t = threadIdx.x;  // 256 threads
    int base = b * 1024 + t * 4;
    int s = 0;
    if (base + 3 < N) {
        int4 v = *(const int4*)(cnt + base);
        s = v.x + v.y + v.z + v.w;
    } else {
        for (int j = 0; j < 4; j++) { int i = base + j; if (i < N) s += cnt[i]; }
    }
#pragma unroll
    for (int o = 32; o; o >>= 1) s += __shfl_down(s, o);
    __shared__ int ws[4];
    if ((t & 63) == 0) ws[t >> 6] = s;
    __syncthreads();
    if (t == 0) bs[b] = ws[0] + ws[1] + ws[2] + ws[3];
}

// Scan of NB (<=128) block sums in one block of 128 threads; writes rp[N]=total.
__global__ void k_bscan(const int* __restrict__ bs, int* __restrict__ bo,
                        int* __restrict__ rp, int NB, int N) {
    int t = threadIdx.x;
    int lane = t & 63;
    int v = (t < NB) ? bs[t] : 0;
    int x = v;
#pragma unroll
    for (int o = 1; o < 64; o <<= 1) { int y = __shfl_up(x, o); if (lane >= o) x += y; }
    __shared__ int w0;
    if (t == 63) w0 = x;
    __syncthreads();
    int pre = (t >= 64) ? w0 : 0;
    if (t < NB) bo[t] = pre + x - v;
    if (t == 127) rp[N] = pre + x;  // grand total
}

// Per-block scan + add block offset; writes rp.
__global__ void k_cscan(const int* __restrict__ cnt, const int* __restrict__ bo,
                        int* __restrict__ rp, int N) {
    int b = blockIdx.x, t = threadIdx.x;  // 256 threads
    int base = b * 1024 + t * 4;
    int v0 = 0, v1 = 0, v2 = 0, v3 = 0;
    if (base + 3 < N) {
        int4 v = *(const int4*)(cnt + base);
        v0 = v.x; v1 = v.y; v2 = v.z; v3 = v.w;
    } else {
        if (base + 0 < N) v0 = cnt[base + 0];
        if (base + 1 < N) v1 = cnt[base + 1];
        if (base + 2 < N) v2 = cnt[base + 2];
        if (base + 3 < N) v3 = cnt[base + 3];
    }
    int s = v0 + v1 + v2 + v3;
    int x = s;
    int lane = t & 63, w = t >> 6;
#pragma unroll
    for (int o = 1; o < 64; o <<= 1) { int y = __shfl_up(x, o); if (lane >= o) x += y; }
    __shared__ int ws[4];
    if (lane == 63) ws[w] = x;
    __syncthreads();
    int pre = 0;
    for (int j = 0; j < w; j++) pre += ws[j];
    int excl = bo[b] + pre + x - s;
    int4 r;
    r.x = excl; r.y = excl + v0; r.z = r.y + v1; r.w = r.z + v2;
    if (base + 3 < N) {
        *(int4*)(rp + base) = r;
    } else {
        if (base + 0 < N) rp[base + 0] = r.x;
        if (base + 1 < N) rp[base + 1] = r.y;
        if (base + 2 < N) rp[base + 2] = r.z;
        if (base + 3 < N) rp[base + 3] = r.w;
    }
}

// Pass 2 (atomic-free): p = rp[dst] + rank; one 8B scatter store per edge.
__global__ void k_fill(const int* __restrict__ src, const int* __restrict__ dst,
                       const float* __restrict__ ew, const int* __restrict__ rank,
                       const int* __restrict__ rp, int2* __restrict__ pay, int E) {
    int e = blockIdx.x * 256 + threadIdx.x;
    if (e < E) {
        int d = dst[e];
        int p = rp[d] + rank[e];   // rp is read-only: L2-replicated, no line bouncing
        int2 pv;
        pv.x = src[e];
        pv.y = __float_as_int(ew[e]);
        pay[p] = pv;
    }
}

// ---------------- GEMM1: h1b[M,128] = bf16( x[M,512] @ W1 )  (bf16 MFMA, no LDS) ----
// C/D: col = lane&15, row = (lane>>4)*4 + reg   [verified layout, learn_hip m89/m91]
__global__ void k_gemm1(const float* __restrict__ x, const __bf16* __restrict__ W1f,
                        __bf16* __restrict__ h1b, int M) {
    int wave = threadIdx.x >> 6;
    int lane = threadIdx.x & 63;
    int q = lane >> 4;
    int col = lane & 15;
    int m0 = blockIdx.x * 64 + wave * 16 + col;  // A-operand row for this lane
    bool valid = (m0 < M);

    f32x4 acc[8];
#pragma unroll
    for (int n = 0; n < 8; n++) acc[n] = (f32x4)(0.0f);

    const bf16x8* Bf = (const bf16x8*)W1f;
    const float* arow = x + (size_t)m0 * NFEAT + q * 8;

    for (int kk = 0; kk < NFEAT; kk += 32) {
        bf16x8 af;
        if (valid) {
            const f32x4* ap = (const f32x4*)(arow + kk);
            f32x4 a0 = __builtin_nontemporal_load(ap);      // x streamed once: keep out of L2
            f32x4 a1 = __builtin_nontemporal_load(ap + 1);
            af[0] = (__bf16)a0[0]; af[1] = (__bf16)a0[1];
            af[2] = (__bf16)a0[2]; af[3] = (__bf16)a0[3];
            af[4] = (__bf16)a1[0]; af[5] = (__bf16)a1[1];
            af[6] = (__bf16)a1[2]; af[7] = (__bf16)a1[3];
        } else {
#pragma unroll
            for (int j = 0; j < 8; j++) af[j] = (__bf16)0.0f;
        }
        int kb = (kk >> 5) * 8;
#pragma unroll
        for (int n = 0; n < 8; n++) {
            bf16x8 bf = Bf[(size_t)(kb + n) * 64 + lane];
            acc[n] = __builtin_amdgcn_mfma_f32_16x16x32_bf16(af, bf, acc[n], 0, 0, 0);
        }
    }

    int rbase = blockIdx.x * 64 + wave * 16 + q * 4;
#pragma unroll
    for (int r = 0; r < 4; r++) {
        int row = rbase + r;
        if (row < M) {
            __bf16* op = h1b + (size_t)row * NHID + col;
#pragma unroll
            for (int n = 0; n < 8; n++) op[n * 16] = (__bf16)acc[n][r];
        }
    }
}

// ---- Agg layer 1 + bias + ReLU + fused GEMM2 (in-wave 128x16 matvec) -> h2 bf16 ----
// One wave per node. Lanes hold features 2*lane, 2*lane+1. After aggregation each
// lane multiplies its 2 features by W2 rows 2*lane/2*lane+1 (held in 32 VGPRs) and
// a 6-step shfl_xor butterfly reduces 16 partials across 64 lanes; lane 0 stores
// the node's 16 bf16 logits (32 B).
__global__ void k_agg1g2(const uint32_t* __restrict__ h1u, const int* __restrict__ rp,
                         const int2* __restrict__ pay, const float* __restrict__ b1,
                         const float* __restrict__ W2, uint32_t* __restrict__ h2b, int N) {
    int gw = (int)((blockIdx.x * (unsigned)blockDim.x + threadIdx.x) >> 6);  // node id
    int lane = threadIdx.x & 63;
    if (gw >= N) return;

    // W2 rows 2*lane and 2*lane+1 (16 floats each); L1-resident (8 KB total).
    float w2a[16], w2b[16];
    {
        const f32x4* W2v = (const f32x4*)W2;
#pragma unroll
        for (int i = 0; i < 4; i++) {
            f32x4 va = W2v[lane * 8 + i];
            f32x4 vb = W2v[lane * 8 + 4 + i];
#pragma unroll
            for (int j = 0; j < 4; j++) { w2a[i * 4 + j] = va[j]; w2b[i * 4 + j] = vb[j]; }
        }
    }

    int s0 = rp[gw], s1 = rp[gw + 1];
    float ax = 0.f, ay = 0.f;
    for (int base = s0; base < s1; base += 64) {
        int cnt = s1 - base;
        if (cnt > 64) cnt = 64;
        int sv = 0;
        float wv = 0.f;
        if (lane < cnt) {
            int2 pv = pay[base + lane];
            sv = pv.x;
            wv = __int_as_float(pv.y);
        }
        int j = 0;
        for (; j + 1 < cnt; j += 2) {   // unroll x2: two independent gathers in flight
            int sA = __shfl(sv, j);     float wA = __shfl(wv, j);
            int sB = __shfl(sv, j + 1); float wB = __shfl(wv, j + 1);
            uint32_t uA = h1u[(size_t)sA * 64 + lane];
            uint32_t uB = h1u[(size_t)sB * 64 + lane];
            ax = fmaf(wA, __uint_as_float(uA << 16), ax);
            ay = fmaf(wA, __uint_as_float(uA & 0xffff0000u), ay);
            ax = fmaf(wB, __uint_as_float(uB << 16), ax);
            ay = fmaf(wB, __uint_as_float(uB & 0xffff0000u), ay);
        }
        if (j < cnt) {
            int s = __shfl(sv, j);
            float ww = __shfl(wv, j);
            uint32_t u = h1u[(size_t)s * 64 + lane];
            ax = fmaf(ww, __uint_as_float(u << 16), ax);
            ay = fmaf(ww, __uint_as_float(u & 0xffff0000u), ay);
        }
    }
    float2 bb = ((const float2*)b1)[lane];
    float hx = fmaxf(ax + bb.x, 0.f);   // h kept fp32 (no bf16 round) -> better accuracy
    float hy = fmaxf(ay + bb.y, 0.f);

    float p[16];
#pragma unroll
    for (int c = 0; c < 16; c++) p[c] = fmaf(hx, w2a[c], hy * w2b[c]);
#pragma unroll
    for (int d = 1; d < 64; d <<= 1) {
#pragma unroll
        for (int c = 0; c < 16; c++) p[c] += __shfl_xor(p[c], d);
    }
    if (lane == 0) {
        union { __bf16 h[16]; uint32_t u[8]; } cv;
#pragma unroll
        for (int c = 0; c < 16; c++) cv.h[c] = (__bf16)p[c];
        uint32_t* op = h2b + (size_t)gw * 8;
        *(uint4*)(op) = make_uint4(cv.u[0], cv.u[1], cv.u[2], cv.u[3]);
        *(uint4*)(op + 4) = make_uint4(cv.u[4], cv.u[5], cv.u[6], cv.u[7]);
    }
}

// ---------------- Agg layer 2 + bias + log_softmax (16 lanes / node) --------
__global__ void k_agg2(const uint16_t* __restrict__ h2h, const int* __restrict__ rp,
                       const int2* __restrict__ pay, const float* __restrict__ b2,
                       float* __restrict__ out, int N) {
    int t = blockIdx.x * 256 + threadIdx.x;
    int node = t >> 4;
    int c = t & 15;
    if (node >= N) return;
    int s0 = rp[node], s1 = rp[node + 1];
    float acc = 0.f;
    for (int i = s0; i < s1; i++) {
        int2 pv = pay[i];   // same addr across the 16 lanes -> broadcast
        uint32_t raw = h2h[(size_t)pv.x * 16 + c];
        acc = fmaf(__int_as_float(pv.y), __uint_as_float(raw << 16), acc);
    }
    float o = acc + b2[c];
    float m = o;
#pragma unroll
    for (int d = 1; d < 16; d <<= 1) m = fmaxf(m, __shfl_xor(m, d));
    float e = expf(o - m);
    float ssum = e;
#pragma unroll
    for (int d = 1; d < 16; d <<= 1) ssum += __shfl_xor(ssum, d);
    out[(size_t)node * NCLASS + c] = o - m - logf(ssum);
}

extern "C" void kernel_launch(void* const* d_in, const int* in_sizes, int n_in,
                              void* d_out, int out_size, void* d_ws, size_t ws_size,
                              hipStream_t stream) {
    const float* x  = (const float*)d_in[0];
    const int*   ei = (const int*)d_in[1];
    const float* ew = (const float*)d_in[2];
    const float* W1 = (const float*)d_in[3];
    const float* b1 = (const float*)d_in[4];
    const float* W2 = (const float*)d_in[5];
    const float* b2 = (const float*)d_in[6];
    float* out = (float*)d_out;

    int N = in_sizes[0] / NFEAT;   // 100000
    int E = in_sizes[2];           // 1600000
    const int* srcI = ei;
    const int* dstI = ei + E;

    char* p = (char*)d_ws;
    auto alloc = [&](size_t bytes) {
        char* r = p;
        p += (bytes + 511) & ~(size_t)511;
        return r;
    };
    __bf16*   h1b  = (__bf16*)alloc((size_t)N * NHID * 2);
    uint32_t* h2b  = (uint32_t*)alloc((size_t)N * 8 * 4);   // 16 bf16 logits / node
    int*      cnt  = (int*)alloc((size_t)N * 4);
    int*      rp   = (int*)alloc(((size_t)N + 1) * 4);
    int*      rank = (int*)alloc((size_t)E * 4);
    int2*     pay  = (int2*)alloc((size_t)E * 8);
    __bf16*   W1f  = (__bf16*)alloc((size_t)NFEAT * NHID * 2);
    int*      bs   = (int*)alloc(1024 * 4);
    int*      bo   = (int*)alloc(1024 * 4);

    int NB = (N + 1023) / 1024;    // 98 blocks (<=128 required by k_bscan)

    (void)hipMemsetAsync(cnt, 0, (size_t)N * 4, stream);
    k_prep_w1<<<32, 256, 0, stream>>>(W1, W1f);

    int eb = (E + 255) / 256;
    k_count_rank<<<eb, 256, 0, stream>>>(dstI, cnt, rank, E);
    k_bsum<<<NB, 256, 0, stream>>>(cnt, bs, N);
    k_bscan<<<1, 128, 0, stream>>>(bs, bo, rp, NB, N);
    k_cscan<<<NB, 256, 0, stream>>>(cnt, bo, rp, N);
    k_fill<<<eb, 256, 0, stream>>>(srcI, dstI, ew, rank, rp, pay, E);

    k_gemm1<<<(N + 63) / 64, 256, 0, stream>>>(x, W1f, h1b, N);
    k_agg1g2<<<(N + 3) / 4, 256, 0, stream>>>((const uint32_t*)h1b, rp, pay, b1, W2, h2b, N);
    k_agg2<<<(int)(((size_t)N * 16 + 255) / 256), 256, 0, stream>>>((const uint16_t*)h2b, rp, pay, b2, out, N);
}

// Round 6
// 633.799 us; speedup vs baseline: 1.0228x; 1.0228x over previous
//
#include <hip/hip_runtime.h>
#include <cstdint>
#include <cstddef>

// GNNGuard: 2-layer GCN, N=100000 nodes, E=1.6M edges, 512->128->16, log_softmax.
// R6: halving butterfly in the fused GEMM2 epilogue (17 shfl vs 96), agg1 gather
// unroll x4, agg2 unroll x4 — all attacking the latency-bound agg kernels.

#define NFEAT 512
#define NHID 128
#define NCLASS 16

typedef __attribute__((ext_vector_type(8))) __bf16 bf16x8;
typedef __attribute__((ext_vector_type(4))) float f32x4;

// ---------------- W1 pre-pack into MFMA B-fragment order ----------------
__global__ void k_prep_w1(const float* __restrict__ W1, __bf16* __restrict__ W1f) {
    int t = blockIdx.x * 256 + threadIdx.x;
    if (t >= 16 * 8 * 64) return;
    int lane = t & 63;
    int nc = (t >> 6) & 7;
    int ks = t >> 9;
    int q = lane >> 4, col = lane & 15;
    __bf16* outp = W1f + (size_t)t * 8;
#pragma unroll
    for (int j = 0; j < 8; j++) {
        int k = ks * 32 + q * 8 + j;
        int n = nc * 16 + col;
        outp[j] = (__bf16)W1[k * NHID + n];
    }
}

// ---------------- CSR build ----------------
__global__ void k_count_rank(const int* __restrict__ dst, int* __restrict__ cnt,
                             int* __restrict__ rank, int E) {
    int e = blockIdx.x * 256 + threadIdx.x;
    if (e < E) rank[e] = atomicAdd(&cnt[dst[e]], 1);
}

__global__ void k_bsum(const int* __restrict__ cnt, int* __restrict__ bs, int N) {
    int b = blockIdx.x, t = threadIdx.x;  // 256 threads
    int base = b * 1024 + t * 4;
    int s = 0;
    if (base + 3 < N) {
        int4 v = *(const int4*)(cnt + base);
        s = v.x + v.y + v.z + v.w;
    } else {
        for (int j = 0; j < 4; j++) { int i = base + j; if (i < N) s += cnt[i]; }
    }
#pragma unroll
    for (int o = 32; o; o >>= 1) s += __shfl_down(s, o);
    __shared__ int ws[4];
    if ((t & 63) == 0) ws[t >> 6] = s;
    __syncthreads();
    if (t == 0) bs[b] = ws[0] + ws[1] + ws[2] + ws[3];
}

__global__ void k_bscan(const int* __restrict__ bs, int* __restrict__ bo,
                        int* __restrict__ rp, int NB, int N) {
    int t = threadIdx.x;
    int lane = t & 63;
    int v = (t < NB) ? bs[t] : 0;
    int x = v;
#pragma unroll
    for (int o = 1; o < 64; o <<= 1) { int y = __shfl_up(x, o); if (lane >= o) x += y; }
    __shared__ int w0;
    if (t == 63) w0 = x;
    __syncthreads();
    int pre = (t >= 64) ? w0 : 0;
    if (t < NB) bo[t] = pre + x - v;
    if (t == 127) rp[N] = pre + x;  // grand total
}

__global__ void k_cscan(const int* __restrict__ cnt, const int* __restrict__ bo,
                        int* __restrict__ rp, int N) {
    int b = blockIdx.x, t = threadIdx.x;  // 256 threads
    int base = b * 1024 + t * 4;
    int v0 = 0, v1 = 0, v2 = 0, v3 = 0;
    if (base + 3 < N) {
        int4 v = *(const int4*)(cnt + base);
        v0 = v.x; v1 = v.y; v2 = v.z; v3 = v.w;
    } else {
        if (base + 0 < N) v0 = cnt[base + 0];
        if (base + 1 < N) v1 = cnt[base + 1];
        if (base + 2 < N) v2 = cnt[base + 2];
        if (base + 3 < N) v3 = cnt[base + 3];
    }
    int s = v0 + v1 + v2 + v3;
    int x = s;
    int lane = t & 63, w = t >> 6;
#pragma unroll
    for (int o = 1; o < 64; o <<= 1) { int y = __shfl_up(x, o); if (lane >= o) x += y; }
    __shared__ int ws[4];
    if (lane == 63) ws[w] = x;
    __syncthreads();
    int pre = 0;
    for (int j = 0; j < w; j++) pre += ws[j];
    int excl = bo[b] + pre + x - s;
    int4 r;
    r.x = excl; r.y = excl + v0; r.z = r.y + v1; r.w = r.z + v2;
    if (base + 3 < N) {
        *(int4*)(rp + base) = r;
    } else {
        if (base + 0 < N) rp[base + 0] = r.x;
        if (base + 1 < N) rp[base + 1] = r.y;
        if (base + 2 < N) rp[base + 2] = r.z;
        if (base + 3 < N) rp[base + 3] = r.w;
    }
}

__global__ void k_fill(const int* __restrict__ src, const int* __restrict__ dst,
                       const float* __restrict__ ew, const int* __restrict__ rank,
                       const int* __restrict__ rp, int2* __restrict__ pay, int E) {
    int e = blockIdx.x * 256 + threadIdx.x;
    if (e < E) {
        int d = dst[e];
        int p = rp[d] + rank[e];
        int2 pv;
        pv.x = src[e];
        pv.y = __float_as_int(ew[e]);
        pay[p] = pv;
    }
}

// ---------------- GEMM1: h1b[M,128] = bf16( x[M,512] @ W1 )  (bf16 MFMA, no LDS) ----
__global__ void k_gemm1(const float* __restrict__ x, const __bf16* __restrict__ W1f,
                        __bf16* __restrict__ h1b, int M) {
    int wave = threadIdx.x >> 6;
    int lane = threadIdx.x & 63;
    int q = lane >> 4;
    int col = lane & 15;
    int m0 = blockIdx.x * 64 + wave * 16 + col;
    bool valid = (m0 < M);

    f32x4 acc[8];
#pragma unroll
    for (int n = 0; n < 8; n++) acc[n] = (f32x4)(0.0f);

    const bf16x8* Bf = (const bf16x8*)W1f;
    const float* arow = x + (size_t)m0 * NFEAT + q * 8;

    for (int kk = 0; kk < NFEAT; kk += 32) {
        bf16x8 af;
        if (valid) {
            const f32x4* ap = (const f32x4*)(arow + kk);
            f32x4 a0 = __builtin_nontemporal_load(ap);
            f32x4 a1 = __builtin_nontemporal_load(ap + 1);
            af[0] = (__bf16)a0[0]; af[1] = (__bf16)a0[1];
            af[2] = (__bf16)a0[2]; af[3] = (__bf16)a0[3];
            af[4] = (__bf16)a1[0]; af[5] = (__bf16)a1[1];
            af[6] = (__bf16)a1[2]; af[7] = (__bf16)a1[3];
        } else {
#pragma unroll
            for (int j = 0; j < 8; j++) af[j] = (__bf16)0.0f;
        }
        int kb = (kk >> 5) * 8;
#pragma unroll
        for (int n = 0; n < 8; n++) {
            bf16x8 bf = Bf[(size_t)(kb + n) * 64 + lane];
            acc[n] = __builtin_amdgcn_mfma_f32_16x16x32_bf16(af, bf, acc[n], 0, 0, 0);
        }
    }

    int rbase = blockIdx.x * 64 + wave * 16 + q * 4;
#pragma unroll
    for (int r = 0; r < 4; r++) {
        int row = rbase + r;
        if (row < M) {
            __bf16* op = h1b + (size_t)row * NHID + col;
#pragma unroll
            for (int n = 0; n < 8; n++) op[n * 16] = (__bf16)acc[n][r];
        }
    }
}

// ---- Agg layer 1 + bias + ReLU + fused GEMM2 -> h2 bf16 ----
// One wave per node; lanes hold features 2*lane, 2*lane+1. Gather loop unrolled x4
// (4 independent L2/L3 gathers in flight). Epilogue: p[16] per lane, then a
// HALVING butterfly (16->8->4->2->1 over xor distances 1,2,4,8 + scalar steps at
// 16,32): 17 shfl total vs 96 for the naive per-class butterfly (R5 regression).
__global__ void k_agg1g2(const uint32_t* __restrict__ h1u, const int* __restrict__ rp,
                         const int2* __restrict__ pay, const float* __restrict__ b1,
                         const float* __restrict__ W2, __bf16* __restrict__ h2b, int N) {
    int gw = (int)((blockIdx.x * (unsigned)blockDim.x + threadIdx.x) >> 6);
    int lane = threadIdx.x & 63;
    if (gw >= N) return;

    // W2 rows 2*lane and 2*lane+1 (16 floats each); L1-resident (8 KB total).
    float w2a[16], w2b[16];
    {
        const f32x4* W2v = (const f32x4*)W2;
#pragma unroll
        for (int i = 0; i < 4; i++) {
            f32x4 va = W2v[lane * 8 + i];
            f32x4 vb = W2v[lane * 8 + 4 + i];
#pragma unroll
            for (int j = 0; j < 4; j++) { w2a[i * 4 + j] = va[j]; w2b[i * 4 + j] = vb[j]; }
        }
    }

    int s0 = rp[gw], s1 = rp[gw + 1];
    float ax = 0.f, ay = 0.f;
    for (int base = s0; base < s1; base += 64) {
        int cnt = s1 - base;
        if (cnt > 64) cnt = 64;
        int sv = 0;
        float wv = 0.f;
        if (lane < cnt) {
            int2 pv = pay[base + lane];
            sv = pv.x;
            wv = __int_as_float(pv.y);
        }
        int j = 0;
        for (; j + 3 < cnt; j += 4) {   // x4: 4 independent gathers in flight
            int sA = __shfl(sv, j);     float wA = __shfl(wv, j);
            int sB = __shfl(sv, j + 1); float wB = __shfl(wv, j + 1);
            int sC = __shfl(sv, j + 2); float wC = __shfl(wv, j + 2);
            int sD = __shfl(sv, j + 3); float wD = __shfl(wv, j + 3);
            uint32_t uA = h1u[(size_t)sA * 64 + lane];
            uint32_t uB = h1u[(size_t)sB * 64 + lane];
            uint32_t uC = h1u[(size_t)sC * 64 + lane];
            uint32_t uD = h1u[(size_t)sD * 64 + lane];
            ax = fmaf(wA, __uint_as_float(uA << 16), ax);
            ay = fmaf(wA, __uint_as_float(uA & 0xffff0000u), ay);
            ax = fmaf(wB, __uint_as_float(uB << 16), ax);
            ay = fmaf(wB, __uint_as_float(uB & 0xffff0000u), ay);
            ax = fmaf(wC, __uint_as_float(uC << 16), ax);
            ay = fmaf(wC, __uint_as_float(uC & 0xffff0000u), ay);
            ax = fmaf(wD, __uint_as_float(uD << 16), ax);
            ay = fmaf(wD, __uint_as_float(uD & 0xffff0000u), ay);
        }
        for (; j < cnt; j++) {
            int s = __shfl(sv, j);
            float ww = __shfl(wv, j);
            uint32_t u = h1u[(size_t)s * 64 + lane];
            ax = fmaf(ww, __uint_as_float(u << 16), ax);
            ay = fmaf(ww, __uint_as_float(u & 0xffff0000u), ay);
        }
    }
    float2 bb = ((const float2*)b1)[lane];
    float hx = fmaxf(ax + bb.x, 0.f);
    float hy = fmaxf(ay + bb.y, 0.f);

    // p[c] = partial logit for class c from this lane's 2 features.
    float p[16];
#pragma unroll
    for (int c = 0; c < 16; c++) p[c] = fmaf(hx, w2a[c], hy * w2b[c]);

    // Halving butterfly. After each step a lane owns half as many classes,
    // selected by its lane bits; send the half the partner owns.
    int b0 = lane & 1, b1_ = (lane >> 1) & 1, b2_ = (lane >> 2) & 1, b3_ = (lane >> 3) & 1;
    float q8[8];
#pragma unroll
    for (int j = 0; j < 8; j++)
        q8[j] = p[j + 8 * b0] + __shfl_xor(p[j + 8 * (1 - b0)], 1);
    float q4[4];
#pragma unroll
    for (int j = 0; j < 4; j++)
        q4[j] = q8[j + 4 * b1_] + __shfl_xor(q8[j + 4 * (1 - b1_)], 2);
    float q2[2];
#pragma unroll
    for (int j = 0; j < 2; j++)
        q2[j] = q4[j + 2 * b2_] + __shfl_xor(q4[j + 2 * (1 - b2_)], 4);
    float q1 = q2[b3_] + __shfl_xor(q2[1 - b3_], 8);
    q1 += __shfl_xor(q1, 16);
    q1 += __shfl_xor(q1, 32);
    // lane < 16 holds class c = b0*8 + b1*4 + b2*2 + b3 (bit-scrambled, all covered)
    if (lane < 16) {
        int c = b0 * 8 + b1_ * 4 + b2_ * 2 + b3_;
        h2b[(size_t)gw * 16 + c] = (__bf16)q1;
    }
}

// ---------------- Agg layer 2 + bias + log_softmax (16 lanes / node) --------
__global__ void k_agg2(const uint16_t* __restrict__ h2h, const int* __restrict__ rp,
                       const int2* __restrict__ pay, const float* __restrict__ b2,
                       float* __restrict__ out, int N) {
    int t = blockIdx.x * 256 + threadIdx.x;
    int node = t >> 4;
    int c = t & 15;
    if (node >= N) return;
    int s0 = rp[node], s1 = rp[node + 1];
    float a0 = 0.f, a1 = 0.f, a2 = 0.f, a3 = 0.f;
    int i = s0;
    for (; i + 3 < s1; i += 4) {   // x4: independent gathers + separate accumulators
        int2 p0 = pay[i], p1 = pay[i + 1], p2 = pay[i + 2], p3 = pay[i + 3];
        uint32_t r0 = h2h[(size_t)p0.x * 16 + c];
        uint32_t r1 = h2h[(size_t)p1.x * 16 + c];
        uint32_t r2 = h2h[(size_t)p2.x * 16 + c];
        uint32_t r3 = h2h[(size_t)p3.x * 16 + c];
        a0 = fmaf(__int_as_float(p0.y), __uint_as_float(r0 << 16), a0);
        a1 = fmaf(__int_as_float(p1.y), __uint_as_float(r1 << 16), a1);
        a2 = fmaf(__int_as_float(p2.y), __uint_as_float(r2 << 16), a2);
        a3 = fmaf(__int_as_float(p3.y), __uint_as_float(r3 << 16), a3);
    }
    for (; i < s1; i++) {
        int2 pv = pay[i];
        uint32_t raw = h2h[(size_t)pv.x * 16 + c];
        a0 = fmaf(__int_as_float(pv.y), __uint_as_float(raw << 16), a0);
    }
    float acc = (a0 + a1) + (a2 + a3);
    float o = acc + b2[c];
    float m = o;
#pragma unroll
    for (int d = 1; d < 16; d <<= 1) m = fmaxf(m, __shfl_xor(m, d));
    float e = expf(o - m);
    float ssum = e;
#pragma unroll
    for (int d = 1; d < 16; d <<= 1) ssum += __shfl_xor(ssum, d);
    out[(size_t)node * NCLASS + c] = o - m - logf(ssum);
}

extern "C" void kernel_launch(void* const* d_in, const int* in_sizes, int n_in,
                              void* d_out, int out_size, void* d_ws, size_t ws_size,
                              hipStream_t stream) {
    const float* x  = (const float*)d_in[0];
    const int*   ei = (const int*)d_in[1];
    const float* ew = (const float*)d_in[2];
    const float* W1 = (const float*)d_in[3];
    const float* b1 = (const float*)d_in[4];
    const float* W2 = (const float*)d_in[5];
    const float* b2 = (const float*)d_in[6];
    float* out = (float*)d_out;

    int N = in_sizes[0] / NFEAT;   // 100000
    int E = in_sizes[2];           // 1600000
    const int* srcI = ei;
    const int* dstI = ei + E;

    char* p = (char*)d_ws;
    auto alloc = [&](size_t bytes) {
        char* r = p;
        p += (bytes + 511) & ~(size_t)511;
        return r;
    };
    __bf16*   h1b  = (__bf16*)alloc((size_t)N * NHID * 2);
    __bf16*   h2b  = (__bf16*)alloc((size_t)N * NCLASS * 2);
    int*      cnt  = (int*)alloc((size_t)N * 4);
    int*      rp   = (int*)alloc(((size_t)N + 1) * 4);
    int*      rank = (int*)alloc((size_t)E * 4);
    int2*     pay  = (int2*)alloc((size_t)E * 8);
    __bf16*   W1f  = (__bf16*)alloc((size_t)NFEAT * NHID * 2);
    int*      bs   = (int*)alloc(1024 * 4);
    int*      bo   = (int*)alloc(1024 * 4);

    int NB = (N + 1023) / 1024;

    (void)hipMemsetAsync(cnt, 0, (size_t)N * 4, stream);
    k_prep_w1<<<32, 256, 0, stream>>>(W1, W1f);

    int eb = (E + 255) / 256;
    k_count_rank<<<eb, 256, 0, stream>>>(dstI, cnt, rank, E);
    k_bsum<<<NB, 256, 0, stream>>>(cnt, bs, N);
    k_bscan<<<1, 128, 0, stream>>>(bs, bo, rp, NB, N);
    k_cscan<<<NB, 256, 0, stream>>>(cnt, bo, rp, N);
    k_fill<<<eb, 256, 0, stream>>>(srcI, dstI, ew, rank, rp, pay, E);

    k_gemm1<<<(N + 63) / 64, 256, 0, stream>>>(x, W1f, h1b, N);
    k_agg1g2<<<(N + 3) / 4, 256, 0, stream>>>((const uint32_t*)h1b, rp, pay, b1, W2, h2b, N);
    k_agg2<<<(int)(((size_t)N * 16 + 255) / 256), 256, 0, stream>>>((const uint16_t*)h2b, rp, pay, b2, out, N);
}